// Round 6
// baseline (74.976 us; speedup 1.0000x reference)
//
#include <hip/hip_runtime.h>

// Shape fixed by reference setup_inputs()
constexpr int B = 4, H = 16, S = 4096, D = 128;
constexpr int BH = B * H;                  // 64 independent sequences
constexpr int CHUNKS = 128;                // chunks along S
constexpr int L = S / CHUNKS;              // 32 rows per chunk
constexpr int D4 = D / 4;                  // 32 float4 lanes cover D
constexpr int UNITS = BH * CHUNKS;         // 8192 (bh, c) units
constexpr int THREADS = UNITS * D4;        // 262144
constexpr int NBLK = THREADS / 256;        // 1024 blocks

typedef float f32x4 __attribute__((ext_vector_type(4)));

__device__ __forceinline__ float4 f4fma(float a, float4 x, float4 y) {
    float4 r;
    r.x = fmaf(a, x.x, y.x);
    r.y = fmaf(a, x.y, y.y);
    r.z = fmaf(a, x.z, y.z);
    r.w = fmaf(a, x.w, y.w);
    return r;
}

// Non-temporal float4 store: y is written once, never re-read this launch;
// nt keeps the write stream from evicting x out of L2/L3.
__device__ __forceinline__ void nt_store4(float4* p, float4 v) {
    union { float4 s; f32x4 v4; } u;
    u.s = v;
    __builtin_nontemporal_store(u.v4, (f32x4*)p);
}

// ---------------------------------------------------------------------------
// Kernel 1: per-chunk carry  A_c[d] = sum_{i<L} gamma^{L-1-i} x[cL+i, d]
// Regular loads: we WANT x resident in L3 for kernel 2's re-read.
// ---------------------------------------------------------------------------
__global__ __launch_bounds__(256) void dc_carry(const float4* __restrict__ x,
                                                const float* __restrict__ gamma,
                                                float4* __restrict__ carries) {
    const int tid  = blockIdx.x * 256 + threadIdx.x;
    const int l    = tid & (D4 - 1);
    const int unit = tid >> 5;                 // (bh, c)
    const int bh   = unit >> 7;                // unit / CHUNKS
    const float g  = gamma[bh & (H - 1)];

    const float4* p = x + (size_t)unit * (L * D4) + l;
    float4 carry = make_float4(0.f, 0.f, 0.f, 0.f);
    // 16-deep batches: loads of a batch issue together, FMA chain trails.
    #pragma unroll
    for (int b = 0; b < L / 16; ++b) {
        float4 v[16];
        #pragma unroll
        for (int i = 0; i < 16; ++i) v[i] = p[(size_t)(b * 16 + i) * D4];
        #pragma unroll
        for (int i = 0; i < 16; ++i) carry = f4fma(g, carry, v[i]);
    }
    carries[(size_t)unit * D4 + l] = carry;
}

// ---------------------------------------------------------------------------
// Kernel 2: issue ALL 32 x-row loads, then the redundant predecessor-carry
// walk (overlapping the in-flight x loads), then consume x from registers:
// run = g*run + x -> y (nt stores).
// ---------------------------------------------------------------------------
__global__ __launch_bounds__(256) void dc_scan(const float4* __restrict__ x,
                                               const float* __restrict__ gamma,
                                               const float4* __restrict__ carries,
                                               float4* __restrict__ y) {
    const int tid  = blockIdx.x * 256 + threadIdx.x;
    const int l    = tid & (D4 - 1);
    const int unit = tid >> 5;
    const int c    = unit & (CHUNKS - 1);
    const int bh   = unit >> 7;
    const float g  = gamma[bh & (H - 1)];

    // gamma^32 via 5 exact squarings; small powers for the 4-way walk
    float gL = g;
    #pragma unroll
    for (int k = 0; k < 5; ++k) gL *= gL;
    const float gL2 = gL * gL;
    const float gL3 = gL2 * gL;
    const float gL4 = gL2 * gL2;

    const size_t base = (size_t)unit * (L * D4) + l;
    const float4* p = x + base;
    float4*       q = y + base;

    // Issue the whole chunk's x loads up front (static indices -> registers).
    float4 v[L];
    #pragma unroll
    for (int i = 0; i < L; ++i) v[i] = p[(size_t)i * D4];

    // Carry walk runs while the x loads are in flight.
    const float4* cp = carries + (size_t)(bh * CHUNKS) * D4 + l;
    float4 P = make_float4(0.f, 0.f, 0.f, 0.f);
    int j = 0;
    for (; j + 4 <= c; j += 4) {
        float4 a0 = cp[(size_t)(j + 0) * D4];
        float4 a1 = cp[(size_t)(j + 1) * D4];
        float4 a2 = cp[(size_t)(j + 2) * D4];
        float4 a3 = cp[(size_t)(j + 3) * D4];
        float4 t = f4fma(gL, a2, a3);
        t = f4fma(gL2, a1, t);
        t = f4fma(gL3, a0, t);
        P = f4fma(gL4, P, t);              // 1 chain-FMA per 4 carries
    }
    for (; j < c; ++j) {
        P = f4fma(gL, P, cp[(size_t)j * D4]);
    }

    // Consume registers with the seeded recurrence.
    float4 run = P;
    #pragma unroll
    for (int i = 0; i < L; ++i) {
        run = f4fma(g, run, v[i]);
        nt_store4(q + (size_t)i * D4, run);
    }
}

extern "C" void kernel_launch(void* const* d_in, const int* in_sizes, int n_in,
                              void* d_out, int out_size, void* d_ws, size_t ws_size,
                              hipStream_t stream) {
    const float4* x     = (const float4*)d_in[0];
    const float*  gamma = (const float*)d_in[1];
    float4*       y     = (float4*)d_out;
    float4*       carries = (float4*)d_ws;   // UNITS * D floats = 4 MiB

    dc_carry<<<NBLK, 256, 0, stream>>>(x, gamma, carries);
    dc_scan<<<NBLK, 256, 0, stream>>>(x, gamma, carries, y);
}

// Round 7
// 74.973 us; speedup vs baseline: 1.0000x; 1.0000x over previous
//
#include <hip/hip_runtime.h>

// Shape fixed by reference setup_inputs()
constexpr int B = 4, H = 16, S = 4096, D = 128;
constexpr int BH = B * H;                  // 64 independent sequences
constexpr int CHUNKS = 128;                // chunks along S
constexpr int L = S / CHUNKS;              // 32 rows per chunk
constexpr int D4 = D / 4;                  // 32 float4 lanes cover D
constexpr int UNITS = BH * CHUNKS;         // 8192 (bh, c) units
constexpr int THREADS = UNITS * D4;        // 262144
constexpr int NBLK = THREADS / 256;        // 1024 blocks
constexpr int UPB = 8;                     // units per 256-thread block

typedef float f32x4 __attribute__((ext_vector_type(4)));

__device__ __forceinline__ float4 f4fma(float a, float4 x, float4 y) {
    float4 r;
    r.x = fmaf(a, x.x, y.x);
    r.y = fmaf(a, x.y, y.y);
    r.z = fmaf(a, x.z, y.z);
    r.w = fmaf(a, x.w, y.w);
    return r;
}

// nt store: y written once, never re-read -> don't evict useful lines.
__device__ __forceinline__ void nt_store4(float4* p, float4 v) {
    union { float4 s; f32x4 v4; } u;
    u.s = v;
    __builtin_nontemporal_store(u.v4, (f32x4*)p);
}

// nt load: x line is dead after this read -> don't let it thrash carries in L2.
__device__ __forceinline__ float4 nt_load4(const float4* p) {
    union { f32x4 v4; float4 s; } u;
    u.v4 = __builtin_nontemporal_load((const f32x4*)p);
    return u.s;
}

// ---------------------------------------------------------------------------
// Kernel 1: per-chunk carry  A_c[d] = sum_{i<L} gamma^{L-1-i} x[cL+i, d]
// Regular loads/stores: we WANT x and carries resident in L3/L2 for kernel 2.
// ---------------------------------------------------------------------------
__global__ __launch_bounds__(256) void dc_carry(const float4* __restrict__ x,
                                                const float* __restrict__ gamma,
                                                float4* __restrict__ carries) {
    const int tid  = blockIdx.x * 256 + threadIdx.x;
    const int l    = tid & (D4 - 1);
    const int unit = tid >> 5;                 // (bh, c)
    const int bh   = unit >> 7;                // unit / CHUNKS
    const float g  = gamma[bh & (H - 1)];

    const float4* p = x + (size_t)unit * (L * D4) + l;
    float4 carry = make_float4(0.f, 0.f, 0.f, 0.f);
    #pragma unroll 8
    for (int i = 0; i < L; ++i) {
        carry = f4fma(g, carry, p[(size_t)i * D4]);
    }
    carries[(size_t)unit * D4 + l] = carry;
}

// ---------------------------------------------------------------------------
// Kernel 2: block-shared carry walk + stream.
//   The 8 units of a block share bh and have consecutive chunks c0..c0+7.
//   Threads 0..31 walk predecessors j<c0 once (4-way reassociated), publish
//   P(c0) via LDS; each unit extends by <=7 exact recurrence steps, then
//   streams its 32 rows: run = g*run + x -> y (nt loads + nt stores).
// ---------------------------------------------------------------------------
__global__ __launch_bounds__(256) void dc_scan(const float4* __restrict__ x,
                                               const float* __restrict__ gamma,
                                               const float4* __restrict__ carries,
                                               float4* __restrict__ y) {
    const int tid  = blockIdx.x * 256 + threadIdx.x;
    const int l    = tid & (D4 - 1);
    const int unit = tid >> 5;
    const int w    = threadIdx.x >> 5;         // unit index within block, 0..7
    const int bh   = unit >> 7;
    const int c0   = (blockIdx.x * UPB) & (CHUNKS - 1);  // block's first chunk
    const float g  = gamma[bh & (H - 1)];

    // gamma^32 via 5 exact squarings; small powers for the 4-way walk
    float gL = g;
    #pragma unroll
    for (int k = 0; k < 5; ++k) gL *= gL;
    const float gL2 = gL * gL;
    const float gL3 = gL2 * gL;
    const float gL4 = gL2 * gL2;

    const size_t base = (size_t)unit * (L * D4) + l;
    const float4* p = x + base;
    float4*       q = y + base;

    // Prefetch the first 8 x rows (in flight across the walk + barrier).
    float4 v0 = nt_load4(p + 0 * D4);
    float4 v1 = nt_load4(p + 1 * D4);
    float4 v2 = nt_load4(p + 2 * D4);
    float4 v3 = nt_load4(p + 3 * D4);
    float4 v4 = nt_load4(p + 4 * D4);
    float4 v5 = nt_load4(p + 5 * D4);
    float4 v6 = nt_load4(p + 6 * D4);
    float4 v7 = nt_load4(p + 7 * D4);

    // --- block-shared walk to P(c0), done once by threads 0..31 ---
    __shared__ float4 Psh[D4];
    if (threadIdx.x < D4) {
        const float4* cp = carries + (size_t)(bh * CHUNKS) * D4 + threadIdx.x;
        float4 P = make_float4(0.f, 0.f, 0.f, 0.f);
        int j = 0;
        for (; j + 4 <= c0; j += 4) {
            float4 a0 = cp[(size_t)(j + 0) * D4];
            float4 a1 = cp[(size_t)(j + 1) * D4];
            float4 a2 = cp[(size_t)(j + 2) * D4];
            float4 a3 = cp[(size_t)(j + 3) * D4];
            float4 t = f4fma(gL, a2, a3);
            t = f4fma(gL2, a1, t);
            t = f4fma(gL3, a0, t);
            P = f4fma(gL4, P, t);          // 1 chain-FMA per 4 carries
        }
        for (; j < c0; ++j) {
            P = f4fma(gL, P, cp[(size_t)j * D4]);
        }
        Psh[threadIdx.x] = P;
    }
    __syncthreads();

    // --- per-unit extension: P(c0+w) = gL*P + A_{c0+i}, i<w (exact) ---
    float4 P = Psh[l];
    const float4* cpl = carries + (size_t)(bh * CHUNKS) * D4 + l;
    for (int i = 0; i < w; ++i) {
        P = f4fma(gL, P, cpl[(size_t)(c0 + i) * D4]);
    }

    // --- stream the chunk with seed P ---
    float4 run = P;
    run = f4fma(g, run, v0); nt_store4(q + 0 * D4, run);
    run = f4fma(g, run, v1); nt_store4(q + 1 * D4, run);
    run = f4fma(g, run, v2); nt_store4(q + 2 * D4, run);
    run = f4fma(g, run, v3); nt_store4(q + 3 * D4, run);
    run = f4fma(g, run, v4); nt_store4(q + 4 * D4, run);
    run = f4fma(g, run, v5); nt_store4(q + 5 * D4, run);
    run = f4fma(g, run, v6); nt_store4(q + 6 * D4, run);
    run = f4fma(g, run, v7); nt_store4(q + 7 * D4, run);
    #pragma unroll 8
    for (int i = 8; i < L; ++i) {
        float4 t = nt_load4(p + (size_t)i * D4);
        run = f4fma(g, run, t);
        nt_store4(q + (size_t)i * D4, run);
    }
}

extern "C" void kernel_launch(void* const* d_in, const int* in_sizes, int n_in,
                              void* d_out, int out_size, void* d_ws, size_t ws_size,
                              hipStream_t stream) {
    const float4* x     = (const float4*)d_in[0];
    const float*  gamma = (const float*)d_in[1];
    float4*       y     = (float4*)d_out;
    float4*       carries = (float4*)d_ws;   // UNITS * D floats = 4 MiB

    dc_carry<<<NBLK, 256, 0, stream>>>(x, gamma, carries);
    dc_scan<<<NBLK, 256, 0, stream>>>(x, gamma, carries, y);
}